// Round 12
// baseline (129.516 us; speedup 1.0000x reference)
//
#include <hip/hip_runtime.h>

typedef __attribute__((ext_vector_type(8))) short short8;
typedef __attribute__((ext_vector_type(4))) float floatx4;

#define FDIM 512
#define HDIM 256

__device__ __forceinline__ unsigned short f2bf(float f) {
  unsigned int u = __float_as_uint(f);
  u += 0x7fffu + ((u >> 16) & 1u);   // round-to-nearest-even
  return (unsigned short)(u >> 16);
}

__device__ __forceinline__ short8 pack2(floatx4 a, floatx4 b) {
  short8 r;
  r[0] = (short)f2bf(a[0]); r[1] = (short)f2bf(a[1]);
  r[2] = (short)f2bf(a[2]); r[3] = (short)f2bf(a[3]);
  r[4] = (short)f2bf(b[0]); r[5] = (short)f2bf(b[1]);
  r[6] = (short)f2bf(b[2]); r[7] = (short)f2bf(b[3]);
  return r;
}

__device__ __forceinline__ float fast_tanh(float x) {
  x = fminf(15.0f, fmaxf(-15.0f, x));
  float e = __expf(2.0f * x);
  return (e - 1.0f) / (e + 1.0f);
}

// A: 2 x global_load_dwordx4 (8 floats), counted in the manual vmcnt ledger.
#define GLOAD_A(r0, r1, p)                                                     \
  do {                                                                         \
    asm volatile("global_load_dwordx4 %0, %1, off"                             \
                 : "=v"(r0) : "v"(p) : "memory");                              \
    asm volatile("global_load_dwordx4 %0, %1, off offset:16"                   \
                 : "=v"(r1) : "v"(p) : "memory");                              \
  } while (0)

// B: 4 x global_load_dwordx4 (4 short8 fragments, 16-col stride = 256 B).
#define GLOAD_B(r, p)                                                          \
  do {                                                                         \
    asm volatile("global_load_dwordx4 %0, %1, off"                             \
                 : "=v"(r[0]) : "v"(p) : "memory");                            \
    asm volatile("global_load_dwordx4 %0, %1, off offset:256"                  \
                 : "=v"(r[1]) : "v"(p) : "memory");                            \
    asm volatile("global_load_dwordx4 %0, %1, off offset:512"                  \
                 : "=v"(r[2]) : "v"(p) : "memory");                            \
    asm volatile("global_load_dwordx4 %0, %1, off offset:768"                  \
                 : "=v"(r[3]) : "v"(p) : "memory");                            \
  } while (0)

// K0: pack W1 [512][256] fp32 -> W1B bf16 fragment-major:
// element index = s*8192 + oct*2048 + n*8 + e   (k = s*32 + oct*8 + e)
// Blocks < 128 also zero `out` (re-poison safety; k3 accumulates atomically).
__global__ void __launch_bounds__(256)
k0_pack_w1(const float* __restrict__ W1, unsigned short* __restrict__ W1B,
           float* __restrict__ out) {
  int tid = threadIdx.x;
  int idx = blockIdx.x * 256 + tid;           // 0..131071
  if (blockIdx.x < 128) out[blockIdx.x * 256 + tid] = 0.0f;   // 32768 floats
  int k = idx >> 8;                           // 0..511
  int n = idx & 255;
  int s = k >> 5, r = k & 31, oct = r >> 3, e = r & 7;
  W1B[s * 8192 + oct * 2048 + n * 8 + e] = f2bf(W1[idx]);
}

// K1: es = exp(score) per row + per-block partial Z.  Loop BYTE-IDENTICAL to
// the R5/R10 proven kernel; only difference: `rowbase`/`pbase` so the launch
// can be split into X-halves for L3 working-set scheduling (see k3 note).
// 64 rows/block, 4 waves, BK=32, 16 steps, LDS ~9 KB, B in registers,
// counted-vmcnt pipeline, no min-waves cap below demand (R4 spill lesson).
// Ledger (A=2 ops, B=4 ops, B depth-1, A depth-2):
//   prologue A0(2) B0(4) A1(2) = 8 outstanding
//   step t head: [A(t)2 B(t)4 A(t+1)2] -> vmcnt(6) retires A(t) (t=15: 4)
//   post-barrier: issue B(t+1) (t<15), A(t+2) (t<14) -> 12 outstanding
//   compute wait: vmcnt(8) retires B(t)  (t=14: 6; t=15: 0)
__global__ void __launch_bounds__(256, 2)
k1_scores(const float* __restrict__ X,
          const unsigned short* __restrict__ W1B,
          const float* __restrict__ b1,
          const float* __restrict__ W2,
          float* __restrict__ es,
          float* __restrict__ partials,
          long rowbase, int pbase) {
  __shared__ __align__(16) unsigned short As[2][2048];  // [buf][row64*32k] = 8 KB
  __shared__ float scpart[256];                         // [wn][row64]

  const int tid  = threadIdx.x;
  const int wn   = tid >> 6;          // 0..3 col-group
  const int lane = tid & 63;
  const int l15  = lane & 15;
  const int l4   = lane >> 4;
  const long row0 = rowbase + (long)blockIdx.x * 64;

  floatx4 acc[4][4];
  #pragma unroll
  for (int m = 0; m < 4; m++)
    #pragma unroll
    for (int n = 0; n < 4; n++)
      acc[m][n] = (floatx4){0.f, 0.f, 0.f, 0.f};

  const int arow = tid >> 2;                    // 0..63
  const int aoct = tid & 3;                     // octet within 32-k step
  const float* xsrc = X + (row0 + arow) * FDIM + aoct * 8;
  const unsigned short* bsrc = W1B + l4 * 2048 + (wn * 64 + l15) * 8;

  floatx4 va0, va1, vb0, vb1;            // 2 rotating A sets (depth-2)
  short8 br0[4], br1[4];                 // 2 rotating B sets (depth-1)

  GLOAD_A(va0, va1, xsrc);
  GLOAD_B(br0, bsrc);
  GLOAD_A(vb0, vb1, xsrc + 32);

  #pragma unroll
  for (int t = 0; t < 16; ++t) {
    if (t < 15) asm volatile("s_waitcnt vmcnt(6)" ::: "memory");
    else        asm volatile("s_waitcnt vmcnt(4)" ::: "memory");
    __builtin_amdgcn_sched_barrier(0);
    {
      short8 a = ((t & 1) == 0) ? pack2(va0, va1) : pack2(vb0, vb1);
      *(short8*)(&As[t & 1][arow * 32 + aoct * 8]) = a;
    }
    asm volatile("s_waitcnt lgkmcnt(0)" ::: "memory");
    __builtin_amdgcn_sched_barrier(0);
    __builtin_amdgcn_s_barrier();
    if (t < 15) {                       // B(t+1) -> other set
      const unsigned short* bp = bsrc + (t + 1) * 8192;
      if (((t + 1) & 1) == 0) GLOAD_B(br0, bp);
      else                    GLOAD_B(br1, bp);
    }
    if (t < 14) {                       // A(t+2) -> just-consumed set
      const float* pp = xsrc + (t + 2) * 32;
      if ((t & 1) == 0) GLOAD_A(va0, va1, pp);
      else              GLOAD_A(vb0, vb1, pp);
    }
    if (t < 14)       asm volatile("s_waitcnt vmcnt(8)" ::: "memory");
    else if (t == 14) asm volatile("s_waitcnt vmcnt(6)" ::: "memory");
    else              asm volatile("s_waitcnt vmcnt(0)" ::: "memory");
    __builtin_amdgcn_sched_barrier(0);
    short8 af[4];
    #pragma unroll
    for (int m = 0; m < 4; ++m)
      af[m] = *(const short8*)(&As[t & 1][(m * 16 + l15) * 32 + l4 * 8]);
    const short8* bcur = ((t & 1) == 0) ? br0 : br1;
    #pragma unroll
    for (int n = 0; n < 4; ++n)
      #pragma unroll
      for (int m = 0; m < 4; ++m)
        acc[m][n] = __builtin_amdgcn_mfma_f32_16x16x32_bf16(af[m], bcur[n], acc[m][n], 0, 0, 0);
  }

  // epilogue: score = sum_c tanh(H + b1[c]) * W2[c]  over this wave's 64 cols
  float rowacc[16];
  #pragma unroll
  for (int i = 0; i < 16; i++) rowacc[i] = 0.f;
  #pragma unroll
  for (int n = 0; n < 4; n++) {
    int c = wn * 64 + n * 16 + l15;
    float b1c = b1[c];
    float w2c = W2[c];
    #pragma unroll
    for (int m = 0; m < 4; m++)
      #pragma unroll
      for (int j = 0; j < 4; j++) {
        float h = fast_tanh(acc[m][n][j] + b1c);
        rowacc[m * 4 + j] = fmaf(h, w2c, rowacc[m * 4 + j]);
      }
  }
  #pragma unroll
  for (int i = 0; i < 16; i++) {
    float v = rowacc[i];
    v += __shfl_xor(v, 1, 64);
    v += __shfl_xor(v, 2, 64);
    v += __shfl_xor(v, 4, 64);
    v += __shfl_xor(v, 8, 64);
    rowacc[i] = v;
  }
  if (l15 == 0) {
    #pragma unroll
    for (int m = 0; m < 4; m++)
      #pragma unroll
      for (int j = 0; j < 4; j++)
        scpart[wn * 64 + m * 16 + l4 * 4 + j] = rowacc[m * 4 + j];
  }
  __syncthreads();

  if (tid < 64) {
    float sv = scpart[0 * 64 + tid] + scpart[1 * 64 + tid] +
               scpart[2 * 64 + tid] + scpart[3 * 64 + tid];
    float ev = __expf(sv);
    es[row0 + tid] = ev;
    float v = ev;
    v += __shfl_xor(v, 1, 64);
    v += __shfl_xor(v, 2, 64);
    v += __shfl_xor(v, 4, 64);
    v += __shfl_xor(v, 8, 64);
    v += __shfl_xor(v, 16, 64);
    v += __shfl_xor(v, 32, 64);
    if (tid == 0) partials[pbase + blockIdx.x] = v;
  }
}

// K3: out[bag] += invZ * sum es[i]*X[i] over chunks with i0 in [lo,hi).
// R10-proven body (folded invZ, atomics).  Launched twice in L3 working-set
// order: k1(H0),k1(H1),k3(H1),k3(H0) — when k3(H1) runs, H1 (134 MB) was the
// last 134 MB streamed and FITS the 256 MB L3 regardless of block order
// (R10/R11 lesson: ~1280 resident blocks destroy any intra-pass stream order,
// so only working-set-level scheduling can raise the ~50% L3 hit rate).
// invZ needs ALL partials: both k1 halves complete before the first k3.
__global__ void __launch_bounds__(256)
k3_bagsum(const float* __restrict__ X, const int* __restrict__ bag_sizes,
          const float* __restrict__ es,
          const float* __restrict__ partials, int nparts,
          float* __restrict__ out, int nbags, int lo, int hi) {
  __shared__ float wred[4];
  __shared__ float invZ_s;
  __shared__ float4 red[128];
  const int tid = threadIdx.x;

  // invZ (folded): sum partials, L2-hot.
  {
    float s = 0.f;
    for (int j = tid; j < nparts; j += 256) s += partials[j];
    #pragma unroll
    for (int m = 1; m < 64; m <<= 1) s += __shfl_xor(s, m, 64);
    if ((tid & 63) == 0) wred[tid >> 6] = s;
    __syncthreads();
    if (tid == 0) invZ_s = 1.0f / (wred[0] + wred[1] + wred[2] + wred[3]);
    __syncthreads();
  }

  const int bag = blockIdx.x >> 4;
  const int ic  = blockIdx.x & 15;
  const int f   = (tid & 127) * 4;     // 0..508
  const int r   = tid >> 7;            // 0 or 1

  int start = 0;
  for (int b = 0; b < bag; ++b) start += bag_sizes[b];
  const int size = bag_sizes[bag];
  const int end = start + size;
  const int chunk = (size + 15) >> 4;
  int i0 = start + ic * chunk;
  int i1 = min(i0 + chunk, end);
  if (i0 < lo || i0 >= hi) return;     // other half's launch handles it

  float ax = 0.f, ay = 0.f, az = 0.f, aw = 0.f;
  for (int i = i0 + r; i < i1; i += 2) {
    float w = es[i];
    float4 x = *(const float4*)(X + (size_t)i * FDIM + f);
    ax = fmaf(x.x, w, ax); ay = fmaf(x.y, w, ay);
    az = fmaf(x.z, w, az); aw = fmaf(x.w, w, aw);
  }
  if (r == 1) red[tid & 127] = (float4){ax, ay, az, aw};
  __syncthreads();
  if (r == 0) {
    float4 o = red[tid];
    float invZ = invZ_s;
    ax = (ax + o.x) * invZ; ay = (ay + o.y) * invZ;
    az = (az + o.z) * invZ; aw = (aw + o.w) * invZ;
    float* op = out + (size_t)bag * FDIM + f;
    atomicAdd(op + 0, ax); atomicAdd(op + 1, ay);
    atomicAdd(op + 2, az); atomicAdd(op + 3, aw);
  }
}

extern "C" void kernel_launch(void* const* d_in, const int* in_sizes, int n_in,
                              void* d_out, int out_size, void* d_ws, size_t ws_size,
                              hipStream_t stream) {
  const float* X         = (const float*)d_in[0];
  const int*   bag_sizes = (const int*)d_in[1];
  const float* W1        = (const float*)d_in[2];
  const float* b1        = (const float*)d_in[3];
  const float* W2        = (const float*)d_in[4];
  // b2 (d_in[5]) cancels in the global softmax — unused.
  float* out = (float*)d_out;

  const int T     = in_sizes[0] / FDIM;   // 131072
  const int nbags = in_sizes[1];          // 64
  const int nblk  = T / 64;               // 2048
  const int hblk  = nblk / 2;             // 1024 blocks per half
  const int lo    = hblk * 64;            // 65536 = half boundary row

  char* ws = (char*)d_ws;
  unsigned short* W1B = (unsigned short*)ws;                     // 262144 B
  float* es       = (float*)(ws + 262144);                       // 524288 B
  float* partials = (float*)(ws + 262144 + 524288);              // 8192 B

  hipLaunchKernelGGL(k0_pack_w1, dim3(512), dim3(256), 0, stream, W1, W1B, out);
  // H0 then H1 scores...
  hipLaunchKernelGGL(k1_scores, dim3(hblk), dim3(256), 0, stream,
                     X, W1B, b1, W2, es, partials, 0L, 0);
  hipLaunchKernelGGL(k1_scores, dim3(nblk - hblk), dim3(256), 0, stream,
                     X, W1B, b1, W2, es, partials, (long)lo, hblk);
  // ...then bag-sum H1 (just-streamed, L3-fit) before H0.
  hipLaunchKernelGGL(k3_bagsum, dim3(nbags * 16), dim3(256), 0, stream,
                     X, bag_sizes, es, partials, nblk, out, nbags, lo, T);
  hipLaunchKernelGGL(k3_bagsum, dim3(nbags * 16), dim3(256), 0, stream,
                     X, bag_sizes, es, partials, nblk, out, nbags, 0, lo);
}

// Round 13
// 106.636 us; speedup vs baseline: 1.2146x; 1.2146x over previous
//
#include <hip/hip_runtime.h>

typedef __attribute__((ext_vector_type(8))) short short8;
typedef __attribute__((ext_vector_type(4))) float floatx4;

#define FDIM 512
#define HDIM 256

__device__ __forceinline__ unsigned short f2bf(float f) {
  unsigned int u = __float_as_uint(f);
  u += 0x7fffu + ((u >> 16) & 1u);   // round-to-nearest-even
  return (unsigned short)(u >> 16);
}

__device__ __forceinline__ short8 pack2(floatx4 a, floatx4 b) {
  short8 r;
  r[0] = (short)f2bf(a[0]); r[1] = (short)f2bf(a[1]);
  r[2] = (short)f2bf(a[2]); r[3] = (short)f2bf(a[3]);
  r[4] = (short)f2bf(b[0]); r[5] = (short)f2bf(b[1]);
  r[6] = (short)f2bf(b[2]); r[7] = (short)f2bf(b[3]);
  return r;
}

__device__ __forceinline__ float fast_tanh(float x) {
  x = fminf(15.0f, fmaxf(-15.0f, x));
  float e = __expf(2.0f * x);
  return (e - 1.0f) / (e + 1.0f);
}

// A: 2 x global_load_dwordx4 (8 floats), counted in the manual vmcnt ledger.
#define GLOAD_A(r0, r1, p)                                                     \
  do {                                                                         \
    asm volatile("global_load_dwordx4 %0, %1, off"                             \
                 : "=v"(r0) : "v"(p) : "memory");                              \
    asm volatile("global_load_dwordx4 %0, %1, off offset:16"                   \
                 : "=v"(r1) : "v"(p) : "memory");                              \
  } while (0)

// B: 4 x global_load_dwordx4 (4 short8 fragments, 16-col stride = 256 B).
#define GLOAD_B(r, p)                                                          \
  do {                                                                         \
    asm volatile("global_load_dwordx4 %0, %1, off"                             \
                 : "=v"(r[0]) : "v"(p) : "memory");                            \
    asm volatile("global_load_dwordx4 %0, %1, off offset:256"                  \
                 : "=v"(r[1]) : "v"(p) : "memory");                            \
    asm volatile("global_load_dwordx4 %0, %1, off offset:512"                  \
                 : "=v"(r[2]) : "v"(p) : "memory");                            \
    asm volatile("global_load_dwordx4 %0, %1, off offset:768"                  \
                 : "=v"(r[3]) : "v"(p) : "memory");                            \
  } while (0)

// K0: pack W1 [512][256] fp32 -> W1B bf16 fragment-major:
// element index = s*8192 + oct*2048 + n*8 + e   (k = s*32 + oct*8 + e)
// Blocks < 128 also zero out (re-poison safety; out accumulated by atomics).
__global__ void __launch_bounds__(256)
k0_pack_w1(const float* __restrict__ W1, unsigned short* __restrict__ W1B,
           float* __restrict__ out) {
  int tid = threadIdx.x;
  int idx = blockIdx.x * 256 + tid;           // 0..131071
  if (blockIdx.x < 128) out[blockIdx.x * 256 + tid] = 0.0f;   // 32768 floats
  int k = idx >> 8;                           // 0..511
  int n = idx & 255;
  int s = k >> 5, r = k & 31, oct = r >> 3, e = r & 7;
  W1B[s * 8192 + oct * 2048 + n * 8 + e] = f2bf(W1[idx]);
}

// K1: es = exp(score) per row + per-block partial Z.  The R5/R10-proven
// kernel (105.97 µs pipeline).  64 rows/block, 4 waves, BK=32, 16 steps,
// LDS ~9 KB, B in registers, counted-vmcnt pipeline, no min-waves cap below
// demand (R4 spill lesson: spilled asm-load regs corrupt the ledger).
// Ledger (A=2 ops, B=4 ops, B depth-1, A depth-2):
//   prologue A0(2) B0(4) A1(2) = 8 outstanding
//   step t head: [A(t)2 B(t)4 A(t+1)2] -> vmcnt(6) retires A(t) (t=15: 4)
//   post-barrier: issue B(t+1) (t<15), A(t+2) (t<14) -> 12 outstanding
//   compute wait: vmcnt(8) retires B(t)  (t=14: 6; t=15: 0)
// WAR on As[t&1]: readers of step t-2 drained via own lgkmcnt(0) before
// barrier(t-1); writer passes barrier(t-1) first -> one barrier/step safe.
__global__ void __launch_bounds__(256, 2)
k1_scores(const float* __restrict__ X,
          const unsigned short* __restrict__ W1B,
          const float* __restrict__ b1,
          const float* __restrict__ W2,
          float* __restrict__ es,
          float* __restrict__ partials) {
  __shared__ __align__(16) unsigned short As[2][2048];  // [buf][row64*32k] = 8 KB
  __shared__ float scpart[256];                         // [wn][row64]

  const int tid  = threadIdx.x;
  const int wn   = tid >> 6;          // 0..3 col-group
  const int lane = tid & 63;
  const int l15  = lane & 15;
  const int l4   = lane >> 4;
  const long row0 = (long)blockIdx.x * 64;

  floatx4 acc[4][4];
  #pragma unroll
  for (int m = 0; m < 4; m++)
    #pragma unroll
    for (int n = 0; n < 4; n++)
      acc[m][n] = (floatx4){0.f, 0.f, 0.f, 0.f};

  const int arow = tid >> 2;                    // 0..63
  const int aoct = tid & 3;                     // octet within 32-k step
  const float* xsrc = X + (row0 + arow) * FDIM + aoct * 8;
  const unsigned short* bsrc = W1B + l4 * 2048 + (wn * 64 + l15) * 8;

  floatx4 va0, va1, vb0, vb1;            // 2 rotating A sets (depth-2)
  short8 br0[4], br1[4];                 // 2 rotating B sets (depth-1)

  GLOAD_A(va0, va1, xsrc);
  GLOAD_B(br0, bsrc);
  GLOAD_A(vb0, vb1, xsrc + 32);

  #pragma unroll
  for (int t = 0; t < 16; ++t) {
    if (t < 15) asm volatile("s_waitcnt vmcnt(6)" ::: "memory");
    else        asm volatile("s_waitcnt vmcnt(4)" ::: "memory");
    __builtin_amdgcn_sched_barrier(0);
    {
      short8 a = ((t & 1) == 0) ? pack2(va0, va1) : pack2(vb0, vb1);
      *(short8*)(&As[t & 1][arow * 32 + aoct * 8]) = a;
    }
    asm volatile("s_waitcnt lgkmcnt(0)" ::: "memory");
    __builtin_amdgcn_sched_barrier(0);
    __builtin_amdgcn_s_barrier();
    if (t < 15) {                       // B(t+1) -> other set
      const unsigned short* bp = bsrc + (t + 1) * 8192;
      if (((t + 1) & 1) == 0) GLOAD_B(br0, bp);
      else                    GLOAD_B(br1, bp);
    }
    if (t < 14) {                       // A(t+2) -> just-consumed set
      const float* pp = xsrc + (t + 2) * 32;
      if ((t & 1) == 0) GLOAD_A(va0, va1, pp);
      else              GLOAD_A(vb0, vb1, pp);
    }
    if (t < 14)       asm volatile("s_waitcnt vmcnt(8)" ::: "memory");
    else if (t == 14) asm volatile("s_waitcnt vmcnt(6)" ::: "memory");
    else              asm volatile("s_waitcnt vmcnt(0)" ::: "memory");
    __builtin_amdgcn_sched_barrier(0);
    short8 af[4];
    #pragma unroll
    for (int m = 0; m < 4; ++m)
      af[m] = *(const short8*)(&As[t & 1][(m * 16 + l15) * 32 + l4 * 8]);
    const short8* bcur = ((t & 1) == 0) ? br0 : br1;
    #pragma unroll
    for (int n = 0; n < 4; ++n)
      #pragma unroll
      for (int m = 0; m < 4; ++m)
        acc[m][n] = __builtin_amdgcn_mfma_f32_16x16x32_bf16(af[m], bcur[n], acc[m][n], 0, 0, 0);
  }

  // epilogue: score = sum_c tanh(H + b1[c]) * W2[c]  over this wave's 64 cols
  float rowacc[16];
  #pragma unroll
  for (int i = 0; i < 16; i++) rowacc[i] = 0.f;
  #pragma unroll
  for (int n = 0; n < 4; n++) {
    int c = wn * 64 + n * 16 + l15;
    float b1c = b1[c];
    float w2c = W2[c];
    #pragma unroll
    for (int m = 0; m < 4; m++)
      #pragma unroll
      for (int j = 0; j < 4; j++) {
        float h = fast_tanh(acc[m][n][j] + b1c);
        rowacc[m * 4 + j] = fmaf(h, w2c, rowacc[m * 4 + j]);
      }
  }
  #pragma unroll
  for (int i = 0; i < 16; i++) {
    float v = rowacc[i];
    v += __shfl_xor(v, 1, 64);
    v += __shfl_xor(v, 2, 64);
    v += __shfl_xor(v, 4, 64);
    v += __shfl_xor(v, 8, 64);
    rowacc[i] = v;
  }
  if (l15 == 0) {
    #pragma unroll
    for (int m = 0; m < 4; m++)
      #pragma unroll
      for (int j = 0; j < 4; j++)
        scpart[wn * 64 + m * 16 + l4 * 4 + j] = rowacc[m * 4 + j];
  }
  __syncthreads();

  // es (global) + block partial Z  (first wave only)
  if (tid < 64) {
    float sv = scpart[0 * 64 + tid] + scpart[1 * 64 + tid] +
               scpart[2 * 64 + tid] + scpart[3 * 64 + tid];
    float ev = __expf(sv);
    es[row0 + tid] = ev;
    float v = ev;
    v += __shfl_xor(v, 1, 64);
    v += __shfl_xor(v, 2, 64);
    v += __shfl_xor(v, 4, 64);
    v += __shfl_xor(v, 8, 64);
    v += __shfl_xor(v, 16, 64);
    v += __shfl_xor(v, 32, 64);
    if (tid == 0) partials[blockIdx.x] = v;
  }
}

// K3 (R10-proven): out[bag] += invZ * sum es[i] * X[i], tail-first mapping,
// folded invZ (per-block redundant reduce of partials, L2-hot).
__global__ void __launch_bounds__(256)
k3_bagsum(const float* __restrict__ X, const int* __restrict__ bag_sizes,
          const float* __restrict__ es,
          const float* __restrict__ partials, int nparts,
          float* __restrict__ out, int nbags) {
  __shared__ float wred[4];
  __shared__ float invZ_s;
  __shared__ float4 red[128];
  const int tid = threadIdx.x;

  {
    float s = 0.f;
    for (int j = tid; j < nparts; j += 256) s += partials[j];
    #pragma unroll
    for (int m = 1; m < 64; m <<= 1) s += __shfl_xor(s, m, 64);
    if ((tid & 63) == 0) wred[tid >> 6] = s;
    __syncthreads();
    if (tid == 0) invZ_s = 1.0f / (wred[0] + wred[1] + wred[2] + wred[3]);
    __syncthreads();
  }

  const int rb  = (int)gridDim.x - 1 - (int)blockIdx.x;   // tail-first
  const int bag = rb >> 4;
  const int ic  = rb & 15;
  const int f   = (tid & 127) * 4;     // 0..508
  const int r   = tid >> 7;            // 0 or 1

  int start = 0;
  for (int b = 0; b < bag; ++b) start += bag_sizes[b];
  const int size = bag_sizes[bag];
  const int end = start + size;
  const int chunk = (size + 15) >> 4;
  int i0 = start + ic * chunk;
  int i1 = min(i0 + chunk, end);

  float ax = 0.f, ay = 0.f, az = 0.f, aw = 0.f;
  const int base = i0 + r;
  if (i1 > base) {
    int i = i1 - 1;
    i -= ((i - base) & 1);             // largest index == base (mod 2)
    for (; i >= base; i -= 2) {        // descending rows
      float w = es[i];
      float4 x = *(const float4*)(X + (size_t)i * FDIM + f);
      ax = fmaf(x.x, w, ax); ay = fmaf(x.y, w, ay);
      az = fmaf(x.z, w, az); aw = fmaf(x.w, w, aw);
    }
  }
  if (r == 1) red[tid & 127] = (float4){ax, ay, az, aw};
  __syncthreads();
  if (r == 0) {
    float4 o = red[tid];
    float invZ = invZ_s;
    ax = (ax + o.x) * invZ; ay = (ay + o.y) * invZ;
    az = (az + o.z) * invZ; aw = (aw + o.w) * invZ;
    float* op = out + (size_t)bag * FDIM + f;
    atomicAdd(op + 0, ax); atomicAdd(op + 1, ay);
    atomicAdd(op + 2, az); atomicAdd(op + 3, aw);
  }
}

extern "C" void kernel_launch(void* const* d_in, const int* in_sizes, int n_in,
                              void* d_out, int out_size, void* d_ws, size_t ws_size,
                              hipStream_t stream) {
  const float* X         = (const float*)d_in[0];
  const int*   bag_sizes = (const int*)d_in[1];
  const float* W1        = (const float*)d_in[2];
  const float* b1        = (const float*)d_in[3];
  const float* W2        = (const float*)d_in[4];
  // b2 (d_in[5]) cancels in the global softmax — unused.
  float* out = (float*)d_out;

  const int T     = in_sizes[0] / FDIM;   // 131072
  const int nbags = in_sizes[1];          // 64
  const int nblk  = T / 64;               // 2048

  char* ws = (char*)d_ws;
  unsigned short* W1B = (unsigned short*)ws;                     // 262144 B
  float* es       = (float*)(ws + 262144);                       // 524288 B
  float* partials = (float*)(ws + 262144 + 524288);              // 8192 B

  hipLaunchKernelGGL(k0_pack_w1, dim3(512), dim3(256), 0, stream, W1, W1B, out);
  hipLaunchKernelGGL(k1_scores, dim3(nblk), dim3(256), 0, stream,
                     X, W1B, b1, W2, es, partials);
  hipLaunchKernelGGL(k3_bagsum, dim3(nbags * 16), dim3(256), 0, stream,
                     X, bag_sizes, es, partials, nblk, out, nbags);
}